// Round 6
// baseline (233.861 us; speedup 1.0000x reference)
//
#include <hip/hip_runtime.h>
#include <hip/hip_bf16.h>

typedef short short8 __attribute__((ext_vector_type(8)));
typedef float f32x4 __attribute__((ext_vector_type(4)));
typedef float f32x16 __attribute__((ext_vector_type(16)));
typedef unsigned int uint4v __attribute__((ext_vector_type(4)));

#define MFMA16(a, b, c) __builtin_amdgcn_mfma_f32_16x16x32_bf16(a, b, c, 0, 0, 0)
#define MFMA32(a, b, c) __builtin_amdgcn_mfma_f32_32x32x16_bf16(a, b, c, 0, 0, 0)

typedef __attribute__((address_space(1))) const unsigned int gas_u32;
typedef __attribute__((address_space(3))) unsigned int las_u32;

__device__ inline void gll16(const void* g, void* l) {
    __builtin_amdgcn_global_load_lds((gas_u32*)g, (las_u32*)l, 16, 0, 0);
}

__device__ inline unsigned short f2bf(float f) {
    unsigned u = __builtin_bit_cast(unsigned, f);
    u += 0x7fff + ((u >> 16) & 1);   // RNE (inputs finite)
    return (unsigned short)(u >> 16);
}

// truncating bf16 pack: low half = a, high half = b
__device__ inline unsigned pk_trunc(float a, float b) {
    unsigned ua = __builtin_bit_cast(unsigned, a);
    unsigned ub = __builtin_bit_cast(unsigned, b);
    return (ua >> 16) | (ub & 0xFFFF0000u);
}

__device__ inline float exp2_fast(float x) {
#if __has_builtin(__builtin_amdgcn_exp2f)
    return __builtin_amdgcn_exp2f(x);
#else
    float r; asm("v_exp_f32 %0, %1" : "=v"(r) : "v"(x)); return r;
#endif
}

// v_permlane32_swap_b32: a's lanes[32:63] <-> b's lanes[0:31]
__device__ inline void pl32_swap(unsigned &a, unsigned &b) {
    asm volatile("v_permlane32_swap_b32 %0, %1" : "+v"(a), "+v"(b));
}

// ------------------------------------------------------------------
// Merged stage 1: x = x + pe[b] (broadcast over s), cast to bf16.  y-dim picks q/k/v.
__global__ void pe_cast3(const float* __restrict__ q, const float* __restrict__ k,
                         const float* __restrict__ v, const float* __restrict__ pe,
                         unsigned short* __restrict__ oq, unsigned short* __restrict__ ok,
                         unsigned short* __restrict__ ov) {
    const float* x = (blockIdx.y == 0) ? q : (blockIdx.y == 1) ? k : v;
    unsigned short* o = (blockIdx.y == 0) ? oq : (blockIdx.y == 1) ? ok : ov;
    int i = blockIdx.x * 256 + threadIdx.x;          // float4 index
    long e = (long)i * 4;
    int b = (int)(e >> 21);
    int d = (int)(e & 1023);
    float4 xv = reinterpret_cast<const float4*>(x)[i];
    float4 pv = *reinterpret_cast<const float4*>(pe + b * 1024 + d);
    ushort4 r;
    r.x = f2bf(xv.x + pv.x); r.y = f2bf(xv.y + pv.y);
    r.z = f2bf(xv.z + pv.z); r.w = f2bf(xv.w + pv.w);
    reinterpret_cast<ushort4*>(o)[i] = r;
}

// Merged stage 2: 4 weight matrices f32 -> bf16.
__global__ void wcast4(const float* __restrict__ w0, const float* __restrict__ w1,
                       const float* __restrict__ w2, const float* __restrict__ w3,
                       unsigned short* __restrict__ o0) {
    const float* w = (blockIdx.y == 0) ? w0 : (blockIdx.y == 1) ? w1
                   : (blockIdx.y == 2) ? w2 : w3;
    unsigned short* o = o0 + (size_t)blockIdx.y * 1024 * 1024;
    int i = blockIdx.x * 256 + threadIdx.x;
    float4 xv = reinterpret_cast<const float4*>(w)[i];
    ushort4 r;
    r.x = f2bf(xv.x); r.y = f2bf(xv.y); r.z = f2bf(xv.z); r.w = f2bf(xv.w);
    reinterpret_cast<ushort4*>(o)[i] = r;
}

// ------------------------------------------------------------------
// Merged Q/K/V projection GEMM (blockIdx.z picks which).
// out[m][n] = (sum_k X[m][k] * W[n][k] + bias[n]) * scale
// z=0: Q -> bf16 head-split [B][H][S][64], scale=0.125*log2e
// z=1: K -> bf16 head-split, scale=1
// z=2: V -> bf16 transposed head-split [B][H][64][S]
__global__ __launch_bounds__(256) void gemm_qkv(const unsigned short* __restrict__ X0,
                                                const unsigned short* __restrict__ W0,
                                                const float* __restrict__ bq,
                                                const float* __restrict__ bk,
                                                const float* __restrict__ bv,
                                                unsigned short* __restrict__ oq,
                                                unsigned short* __restrict__ ok,
                                                unsigned short* __restrict__ ov,
                                                float qscale) {
    const int K = 1024;
    int z = blockIdx.z;
    const unsigned short* A = X0 + (size_t)z * 8192 * 1024;
    const unsigned short* W = W0 + (size_t)z * 1024 * 1024;
    const float* bias = (z == 0) ? bq : (z == 1) ? bk : bv;
    unsigned short* out = (z == 0) ? oq : (z == 1) ? ok : ov;
    float scale = (z == 0) ? qscale : 1.0f;

    __shared__ unsigned short lsA[128 * 32];
    __shared__ unsigned short lsB[128 * 32];
    int tid = threadIdx.x;
    int wave = tid >> 6, lane = tid & 63, lg = lane >> 4, l15 = lane & 15;
    int brow = blockIdx.x * 128;
    int bcol = blockIdx.y * 128;
    int wr = wave >> 1, wc = wave & 1;

    f32x4 zero4 = {0.f, 0.f, 0.f, 0.f};
    f32x4 acc[4][4];
#pragma unroll
    for (int m = 0; m < 4; ++m)
#pragma unroll
        for (int n = 0; n < 4; ++n) acc[m][n] = zero4;

    for (int k0 = 0; k0 < K; k0 += 32) {
#pragma unroll
        for (int j = 0; j < 2; ++j) {
            int c = j * 256 + wave * 64 + lane;
            const unsigned short* srcA = A + ((long)(brow + (c >> 2)) * K + k0 + (c & 3) * 8);
            const unsigned short* srcB = W + ((long)(bcol + (c >> 2)) * K + k0 + (c & 3) * 8);
            char* dstA = (char*)lsA + (j * 256 + wave * 64) * 16;   // wave-uniform base
            char* dstB = (char*)lsB + (j * 256 + wave * 64) * 16;
            gll16(srcA, dstA);
            gll16(srcB, dstB);
        }
        __syncthreads();
        short8 af[4], bf_[4];
#pragma unroll
        for (int m = 0; m < 4; ++m) {
            int row = wr * 64 + m * 16 + l15;
            af[m] = *(const short8*)((const char*)lsA + row * 64 + lg * 16);
        }
#pragma unroll
        for (int n = 0; n < 4; ++n) {
            int col = wc * 64 + n * 16 + l15;
            bf_[n] = *(const short8*)((const char*)lsB + col * 64 + lg * 16);
        }
#pragma unroll
        for (int m = 0; m < 4; ++m)
#pragma unroll
            for (int n = 0; n < 4; ++n) acc[m][n] = MFMA16(af[m], bf_[n], acc[m][n]);
        __syncthreads();
    }

#pragma unroll
    for (int m = 0; m < 4; ++m)
#pragma unroll
        for (int n = 0; n < 4; ++n) {
            int col = bcol + wc * 64 + n * 16 + l15;
            float bv_ = bias[col];
#pragma unroll
            for (int r = 0; r < 4; ++r) {
                int row = brow + wr * 64 + m * 16 + lg * 4 + r;
                float v = (acc[m][n][r] + bv_) * scale;
                int b = row >> 11, s = row & 2047;
                if (z < 2) {
                    int h = col >> 6, d = col & 63;
                    out[(((long)(b * 16 + h) * 2048 + s) * 64 + d)] = f2bf(v);
                } else {
                    out[((long)(b * 1024 + col)) * 2048 + s] = f2bf(v);   // V^T
                }
            }
        }
}

// Final dense GEMM -> f32
__global__ __launch_bounds__(256) void gemm_dense(const unsigned short* __restrict__ A,
                                                  const unsigned short* __restrict__ W,
                                                  const float* __restrict__ bias,
                                                  float* __restrict__ out) {
    const int K = 1024;
    __shared__ unsigned short lsA[128 * 32];
    __shared__ unsigned short lsB[128 * 32];
    int tid = threadIdx.x;
    int wave = tid >> 6, lane = tid & 63, lg = lane >> 4, l15 = lane & 15;
    int brow = blockIdx.x * 128;
    int bcol = blockIdx.y * 128;
    int wr = wave >> 1, wc = wave & 1;

    f32x4 zero4 = {0.f, 0.f, 0.f, 0.f};
    f32x4 acc[4][4];
#pragma unroll
    for (int m = 0; m < 4; ++m)
#pragma unroll
        for (int n = 0; n < 4; ++n) acc[m][n] = zero4;

    for (int k0 = 0; k0 < K; k0 += 32) {
#pragma unroll
        for (int j = 0; j < 2; ++j) {
            int c = j * 256 + wave * 64 + lane;
            const unsigned short* srcA = A + ((long)(brow + (c >> 2)) * K + k0 + (c & 3) * 8);
            const unsigned short* srcB = W + ((long)(bcol + (c >> 2)) * K + k0 + (c & 3) * 8);
            char* dstA = (char*)lsA + (j * 256 + wave * 64) * 16;
            char* dstB = (char*)lsB + (j * 256 + wave * 64) * 16;
            gll16(srcA, dstA);
            gll16(srcB, dstB);
        }
        __syncthreads();
        short8 af[4], bf_[4];
#pragma unroll
        for (int m = 0; m < 4; ++m) {
            int row = wr * 64 + m * 16 + l15;
            af[m] = *(const short8*)((const char*)lsA + row * 64 + lg * 16);
        }
#pragma unroll
        for (int n = 0; n < 4; ++n) {
            int col = wc * 64 + n * 16 + l15;
            bf_[n] = *(const short8*)((const char*)lsB + col * 64 + lg * 16);
        }
#pragma unroll
        for (int m = 0; m < 4; ++m)
#pragma unroll
            for (int n = 0; n < 4; ++n) acc[m][n] = MFMA16(af[m], bf_[n], acc[m][n]);
        __syncthreads();
    }

#pragma unroll
    for (int m = 0; m < 4; ++m)
#pragma unroll
        for (int n = 0; n < 4; ++n) {
            int col = bcol + wc * 64 + n * 16 + l15;
            float bv = bias[col];
#pragma unroll
            for (int r = 0; r < 4; ++r) {
                int row = brow + wr * 64 + m * 16 + lg * 4 + r;
                out[(long)row * 1024 + col] = acc[m][n][r] + bv;
            }
        }
}

// ------------------------------------------------------------------
// Flash attention, 32x32x16 MFMA, swapped QK^T, in-register P via permlane,
// MFMA row-sums, no-max exp2 softmax, pre-transposed V.
// 3-buffer depth-2 prefetch with counted vmcnt (T3/T4): never drain to 0 mid-loop.
__global__ __launch_bounds__(256) void attn_kernel(const unsigned short* __restrict__ Qh,
                                                   const unsigned short* __restrict__ Kh,
                                                   const unsigned short* __restrict__ Vt,
                                                   unsigned short* __restrict__ Om) {
    const int S = 2048;
    const int NT = S / 64;
    int flat = blockIdx.x;
    int nf_ = (flat & 7) * 128 + (flat >> 3);   // 8 XCDs x 128 contiguous
    int qt = nf_ & 15;
    int bh = nf_ >> 4;
    int b = bh >> 4, h = bh & 15;

    int tid = threadIdx.x, wave = tid >> 6, lane = tid & 63;
    int l31 = lane & 31, hi = lane >> 5;

    __shared__ __align__(16) unsigned short Kl[3][4096];    // [kv][d] ^((kv&7)<<4)
    __shared__ __align__(16) unsigned short Vtl[3][4096];   // [d][kv] ^((d&7)<<4)

    const unsigned short* Qb = Qh + (long)bh * S * 64;
    const unsigned short* Kb = Kh + (long)bh * S * 64;
    const unsigned short* Vb = Vt + (long)bh * 64 * S;

    // pre-swizzled global sources (swizzle-on-source + swizzle-on-read, linear LDS dest)
    int colS = ((((tid & 7) * 16) ^ (((tid >> 3) & 7) << 4)) >> 1);   // elems
    const unsigned short* srcK = Kb + (tid >> 3) * 64 + colS;         // + kt*4096; i=1:+2048
    const unsigned short* srcV = Vb + (tid >> 3) * 2048 + colS;       // + kt*64;   i=1:+65536

    // Q B-fragments in registers: B[j=q=l31][k=d], k-slice s: d = s*16 + hi*8 + e
    short8 aq[4];
    {
        const unsigned short* qrow = Qb + (long)(qt * 128 + wave * 32 + l31) * 64 + hi * 8;
#pragma unroll
        for (int s = 0; s < 4; ++s) aq[s] = *(const short8*)(qrow + s * 16);
    }

    f32x16 oacc[2], lacc;
#pragma unroll
    for (int r = 0; r < 16; ++r) { oacc[0][r] = 0.f; oacc[1][r] = 0.f; lacc[r] = 0.f; }

    const short8 ones8 = {0x3F80, 0x3F80, 0x3F80, 0x3F80, 0x3F80, 0x3F80, 0x3F80, 0x3F80};

    int rb0 = l31 * 128;                 // row byte (within 32-row block)
    int swz = (l31 & 7) << 4;

#define STAGE(kt, bi) do {                                              \
        const unsigned short* sk = srcK + (kt) * 4096;                  \
        gll16(sk,         (char*)Kl[bi] + wave * 1024);                 \
        gll16(sk + 2048,  (char*)Kl[bi] + 4096 + wave * 1024);          \
        const unsigned short* sv = srcV + (kt) * 64;                    \
        gll16(sv,         (char*)Vtl[bi] + wave * 1024);                \
        gll16(sv + 65536, (char*)Vtl[bi] + 4096 + wave * 1024);         \
    } while (0)

    STAGE(0, 0);
    STAGE(1, 1);

    int bi = 0, sb = 2;                  // compute buffer, stage buffer (kt+2)%3
    for (int kt = 0; kt < NT; ++kt) {
        // oldest 4 loads (this tile) complete; keep next tile's 4 in flight
        if (kt == NT - 1) { asm volatile("s_waitcnt vmcnt(0)" ::: "memory"); }
        else              { asm volatile("s_waitcnt vmcnt(4)" ::: "memory"); }
        __builtin_amdgcn_s_barrier();
        // safe to overwrite buffer read 2 iterations ago: all waves passed that
        // iteration's reads (lgkm-consumed) before reaching this barrier.
        if (kt < NT - 2) STAGE(kt + 2, sb);

        const char* KlC = (const char*)Kl[bi];
        const char* VlC = (const char*)Vtl[bi];

        // ---- S^T = K Q^T ----
        f32x16 sacc[2];
#pragma unroll
        for (int r = 0; r < 16; ++r) { sacc[0][r] = 0.f; sacc[1][r] = 0.f; }
#pragma unroll
        for (int blk = 0; blk < 2; ++blk)
#pragma unroll
            for (int s = 0; s < 4; ++s) {
                short8 kf = *(const short8*)(KlC + blk * 4096 + rb0 + ((32 * s + 16 * hi) ^ swz));
                sacc[blk] = MFMA32(kf, aq[s], sacc[blk]);
            }

        // ---- P = exp2(S^T) (Q pre-scaled by 0.125*log2e; no max needed) ----
#pragma unroll
        for (int blk = 0; blk < 2; ++blk)
#pragma unroll
            for (int r = 0; r < 16; ++r) sacc[blk][r] = exp2_fast(sacc[blk][r]);

        // ---- per 16-kv slice: pack, permlane32_swap -> PV A-frag; 3 MFMAs ----
#pragma unroll
        for (int s = 0; s < 4; ++s) {
            const int blk = s >> 1, base = (s & 1) * 8;
            unsigned q0 = pk_trunc(sacc[blk][base + 0], sacc[blk][base + 1]);
            unsigned q1 = pk_trunc(sacc[blk][base + 2], sacc[blk][base + 3]);
            unsigned q2 = pk_trunc(sacc[blk][base + 4], sacc[blk][base + 5]);
            unsigned q3 = pk_trunc(sacc[blk][base + 6], sacc[blk][base + 7]);
            pl32_swap(q0, q2);
            pl32_swap(q1, q3);
            uint4v pw; pw[0] = q0; pw[1] = q1; pw[2] = q2; pw[3] = q3;
            short8 pa = __builtin_bit_cast(short8, pw);
#pragma unroll
            for (int dblk = 0; dblk < 2; ++dblk) {
                short8 vf = *(const short8*)(VlC + dblk * 4096 + rb0 + ((32 * s + 16 * hi) ^ swz));
                oacc[dblk] = MFMA32(pa, vf, oacc[dblk]);
            }
            lacc = MFMA32(pa, ones8, lacc);   // row-sums, C-layout aligned with oacc
        }
        bi = (bi == 2) ? 0 : bi + 1;
        sb = (sb == 2) ? 0 : sb + 1;
    }
#undef STAGE

    // ---- normalize + store merged [B][S][1024] ----
    float inv[16];
#pragma unroll
    for (int r = 0; r < 16; ++r) inv[r] = 1.0f / lacc[r];

    int qrow0 = qt * 128 + wave * 32 + 4 * hi;
#pragma unroll
    for (int dblk = 0; dblk < 2; ++dblk)
#pragma unroll
        for (int r = 0; r < 16; ++r) {
            int qrow = qrow0 + (r & 3) + 8 * (r >> 2);
            int d = h * 64 + dblk * 32 + l31;
            float v = oacc[dblk][r] * inv[r];
            Om[((long)b * 2048 + qrow) * 1024 + d] = f2bf(v);
        }
}

// ------------------------------------------------------------------
extern "C" void kernel_launch(void* const* d_in, const int* in_sizes, int n_in,
                              void* d_out, int out_size, void* d_ws, size_t ws_size,
                              hipStream_t stream) {
    const float* v_in = (const float*)d_in[0];
    const float* k_in = (const float*)d_in[1];
    const float* q_in = (const float*)d_in[2];
    const float* wq_w = (const float*)d_in[3];
    const float* wq_b = (const float*)d_in[4];
    const float* wk_w = (const float*)d_in[5];
    const float* wk_b = (const float*)d_in[6];
    const float* wv_w = (const float*)d_in[7];
    const float* wv_b = (const float*)d_in[8];
    const float* wd_w = (const float*)d_in[9];
    const float* wd_b = (const float*)d_in[10];
    const float* pe   = (const float*)d_in[11];

    const long SZ = 8192L * 1024 * 2;
    char* ws = (char*)d_ws;
    unsigned short* xq = (unsigned short*)(ws + 0);          // xq,xk,xv contiguous
    unsigned short* xk = (unsigned short*)(ws + SZ);
    unsigned short* xv = (unsigned short*)(ws + 2 * SZ);
    unsigned short* qh = (unsigned short*)(ws + 3 * SZ);
    unsigned short* kh = (unsigned short*)(ws + 4 * SZ);
    unsigned short* vt = (unsigned short*)(ws + 5 * SZ);
    unsigned short* wqb16 = (unsigned short*)(ws + 6 * SZ);  // wq,wk,wv,wd contiguous

    pe_cast3<<<dim3(8192, 3), 256, 0, stream>>>(q_in, k_in, v_in, pe, xq, xk, xv);
    wcast4<<<dim3(1024, 4), 256, 0, stream>>>(wq_w, wk_w, wv_w, wd_w, wqb16);

    const float QSCALE = 0.125f * 1.44269504088896f;   // fold 1/sqrt(64) * log2(e)
    gemm_qkv<<<dim3(64, 8, 3), 256, 0, stream>>>(xq, wqb16, wq_b, wk_b, wv_b,
                                                 qh, kh, vt, QSCALE);
    unsigned short* om = xq;
    attn_kernel<<<1024, 256, 0, stream>>>(qh, kh, vt, om);
    gemm_dense<<<dim3(64, 8), 256, 0, stream>>>(om, wqb16 + 3L * 1024 * 1024, wd_b,
                                                (float*)d_out);
}

// Round 7
// 219.558 us; speedup vs baseline: 1.0651x; 1.0651x over previous
//
#include <hip/hip_runtime.h>
#include <hip/hip_bf16.h>

typedef short short8 __attribute__((ext_vector_type(8)));
typedef float f32x4 __attribute__((ext_vector_type(4)));
typedef float f32x16 __attribute__((ext_vector_type(16)));
typedef unsigned int uint4v __attribute__((ext_vector_type(4)));

#define MFMA16(a, b, c) __builtin_amdgcn_mfma_f32_16x16x32_bf16(a, b, c, 0, 0, 0)
#define MFMA32(a, b, c) __builtin_amdgcn_mfma_f32_32x32x16_bf16(a, b, c, 0, 0, 0)

typedef __attribute__((address_space(1))) const unsigned int gas_u32;
typedef __attribute__((address_space(3))) unsigned int las_u32;

__device__ inline void gll16(const void* g, void* l) {
    __builtin_amdgcn_global_load_lds((gas_u32*)g, (las_u32*)l, 16, 0, 0);
}

__device__ inline unsigned short f2bf(float f) {
    unsigned u = __builtin_bit_cast(unsigned, f);
    u += 0x7fff + ((u >> 16) & 1);   // RNE (inputs finite)
    return (unsigned short)(u >> 16);
}

// truncating bf16 pack: low half = a, high half = b
__device__ inline unsigned pk_trunc(float a, float b) {
    unsigned ua = __builtin_bit_cast(unsigned, a);
    unsigned ub = __builtin_bit_cast(unsigned, b);
    return (ua >> 16) | (ub & 0xFFFF0000u);
}

__device__ inline float exp2_fast(float x) {
#if __has_builtin(__builtin_amdgcn_exp2f)
    return __builtin_amdgcn_exp2f(x);
#else
    float r; asm("v_exp_f32 %0, %1" : "=v"(r) : "v"(x)); return r;
#endif
}

// v_permlane32_swap_b32: a's lanes[32:63] <-> b's lanes[0:31]
__device__ inline void pl32_swap(unsigned &a, unsigned &b) {
    asm volatile("v_permlane32_swap_b32 %0, %1" : "+v"(a), "+v"(b));
}

// ------------------------------------------------------------------
// Merged stage 1: x = x + pe[b] (broadcast over s), cast to bf16.  y-dim picks q/k/v.
__global__ void pe_cast3(const float* __restrict__ q, const float* __restrict__ k,
                         const float* __restrict__ v, const float* __restrict__ pe,
                         unsigned short* __restrict__ oq, unsigned short* __restrict__ ok,
                         unsigned short* __restrict__ ov) {
    const float* x = (blockIdx.y == 0) ? q : (blockIdx.y == 1) ? k : v;
    unsigned short* o = (blockIdx.y == 0) ? oq : (blockIdx.y == 1) ? ok : ov;
    int i = blockIdx.x * 256 + threadIdx.x;          // float4 index
    long e = (long)i * 4;
    int b = (int)(e >> 21);
    int d = (int)(e & 1023);
    float4 xv = reinterpret_cast<const float4*>(x)[i];
    float4 pv = *reinterpret_cast<const float4*>(pe + b * 1024 + d);
    ushort4 r;
    r.x = f2bf(xv.x + pv.x); r.y = f2bf(xv.y + pv.y);
    r.z = f2bf(xv.z + pv.z); r.w = f2bf(xv.w + pv.w);
    reinterpret_cast<ushort4*>(o)[i] = r;
}

// Merged stage 2: 4 weight matrices f32 -> bf16.
__global__ void wcast4(const float* __restrict__ w0, const float* __restrict__ w1,
                       const float* __restrict__ w2, const float* __restrict__ w3,
                       unsigned short* __restrict__ o0) {
    const float* w = (blockIdx.y == 0) ? w0 : (blockIdx.y == 1) ? w1
                   : (blockIdx.y == 2) ? w2 : w3;
    unsigned short* o = o0 + (size_t)blockIdx.y * 1024 * 1024;
    int i = blockIdx.x * 256 + threadIdx.x;
    float4 xv = reinterpret_cast<const float4*>(w)[i];
    ushort4 r;
    r.x = f2bf(xv.x); r.y = f2bf(xv.y); r.z = f2bf(xv.z); r.w = f2bf(xv.w);
    reinterpret_cast<ushort4*>(o)[i] = r;
}

// ------------------------------------------------------------------
// Merged Q/K/V projection GEMM (blockIdx.z picks which).
__global__ __launch_bounds__(256) void gemm_qkv(const unsigned short* __restrict__ X0,
                                                const unsigned short* __restrict__ W0,
                                                const float* __restrict__ bq,
                                                const float* __restrict__ bk,
                                                const float* __restrict__ bv,
                                                unsigned short* __restrict__ oq,
                                                unsigned short* __restrict__ ok,
                                                unsigned short* __restrict__ ov,
                                                float qscale) {
    const int K = 1024;
    int z = blockIdx.z;
    const unsigned short* A = X0 + (size_t)z * 8192 * 1024;
    const unsigned short* W = W0 + (size_t)z * 1024 * 1024;
    const float* bias = (z == 0) ? bq : (z == 1) ? bk : bv;
    unsigned short* out = (z == 0) ? oq : (z == 1) ? ok : ov;
    float scale = (z == 0) ? qscale : 1.0f;

    __shared__ unsigned short lsA[128 * 32];
    __shared__ unsigned short lsB[128 * 32];
    int tid = threadIdx.x;
    int wave = tid >> 6, lane = tid & 63, lg = lane >> 4, l15 = lane & 15;
    int brow = blockIdx.x * 128;
    int bcol = blockIdx.y * 128;
    int wr = wave >> 1, wc = wave & 1;

    f32x4 zero4 = {0.f, 0.f, 0.f, 0.f};
    f32x4 acc[4][4];
#pragma unroll
    for (int m = 0; m < 4; ++m)
#pragma unroll
        for (int n = 0; n < 4; ++n) acc[m][n] = zero4;

    for (int k0 = 0; k0 < K; k0 += 32) {
#pragma unroll
        for (int j = 0; j < 2; ++j) {
            int c = j * 256 + wave * 64 + lane;
            const unsigned short* srcA = A + ((long)(brow + (c >> 2)) * K + k0 + (c & 3) * 8);
            const unsigned short* srcB = W + ((long)(bcol + (c >> 2)) * K + k0 + (c & 3) * 8);
            char* dstA = (char*)lsA + (j * 256 + wave * 64) * 16;   // wave-uniform base
            char* dstB = (char*)lsB + (j * 256 + wave * 64) * 16;
            gll16(srcA, dstA);
            gll16(srcB, dstB);
        }
        __syncthreads();
        short8 af[4], bf_[4];
#pragma unroll
        for (int m = 0; m < 4; ++m) {
            int row = wr * 64 + m * 16 + l15;
            af[m] = *(const short8*)((const char*)lsA + row * 64 + lg * 16);
        }
#pragma unroll
        for (int n = 0; n < 4; ++n) {
            int col = wc * 64 + n * 16 + l15;
            bf_[n] = *(const short8*)((const char*)lsB + col * 64 + lg * 16);
        }
#pragma unroll
        for (int m = 0; m < 4; ++m)
#pragma unroll
            for (int n = 0; n < 4; ++n) acc[m][n] = MFMA16(af[m], bf_[n], acc[m][n]);
        __syncthreads();
    }

#pragma unroll
    for (int m = 0; m < 4; ++m)
#pragma unroll
        for (int n = 0; n < 4; ++n) {
            int col = bcol + wc * 64 + n * 16 + l15;
            float bv_ = bias[col];
#pragma unroll
            for (int r = 0; r < 4; ++r) {
                int row = brow + wr * 64 + m * 16 + lg * 4 + r;
                float v = (acc[m][n][r] + bv_) * scale;
                int b = row >> 11, s = row & 2047;
                if (z < 2) {
                    int h = col >> 6, d = col & 63;
                    out[(((long)(b * 16 + h) * 2048 + s) * 64 + d)] = f2bf(v);
                } else {
                    out[((long)(b * 1024 + col)) * 2048 + s] = f2bf(v);   // V^T
                }
            }
        }
}

// Final dense GEMM -> f32
__global__ __launch_bounds__(256) void gemm_dense(const unsigned short* __restrict__ A,
                                                  const unsigned short* __restrict__ W,
                                                  const float* __restrict__ bias,
                                                  float* __restrict__ out) {
    const int K = 1024;
    __shared__ unsigned short lsA[128 * 32];
    __shared__ unsigned short lsB[128 * 32];
    int tid = threadIdx.x;
    int wave = tid >> 6, lane = tid & 63, lg = lane >> 4, l15 = lane & 15;
    int brow = blockIdx.x * 128;
    int bcol = blockIdx.y * 128;
    int wr = wave >> 1, wc = wave & 1;

    f32x4 zero4 = {0.f, 0.f, 0.f, 0.f};
    f32x4 acc[4][4];
#pragma unroll
    for (int m = 0; m < 4; ++m)
#pragma unroll
        for (int n = 0; n < 4; ++n) acc[m][n] = zero4;

    for (int k0 = 0; k0 < K; k0 += 32) {
#pragma unroll
        for (int j = 0; j < 2; ++j) {
            int c = j * 256 + wave * 64 + lane;
            const unsigned short* srcA = A + ((long)(brow + (c >> 2)) * K + k0 + (c & 3) * 8);
            const unsigned short* srcB = W + ((long)(bcol + (c >> 2)) * K + k0 + (c & 3) * 8);
            char* dstA = (char*)lsA + (j * 256 + wave * 64) * 16;
            char* dstB = (char*)lsB + (j * 256 + wave * 64) * 16;
            gll16(srcA, dstA);
            gll16(srcB, dstB);
        }
        __syncthreads();
        short8 af[4], bf_[4];
#pragma unroll
        for (int m = 0; m < 4; ++m) {
            int row = wr * 64 + m * 16 + l15;
            af[m] = *(const short8*)((const char*)lsA + row * 64 + lg * 16);
        }
#pragma unroll
        for (int n = 0; n < 4; ++n) {
            int col = wc * 64 + n * 16 + l15;
            bf_[n] = *(const short8*)((const char*)lsB + col * 64 + lg * 16);
        }
#pragma unroll
        for (int m = 0; m < 4; ++m)
#pragma unroll
            for (int n = 0; n < 4; ++n) acc[m][n] = MFMA16(af[m], bf_[n], acc[m][n]);
        __syncthreads();
    }

#pragma unroll
    for (int m = 0; m < 4; ++m)
#pragma unroll
        for (int n = 0; n < 4; ++n) {
            int col = bcol + wc * 64 + n * 16 + l15;
            float bv = bias[col];
#pragma unroll
            for (int r = 0; r < 4; ++r) {
                int row = brow + wr * 64 + m * 16 + lg * 4 + r;
                out[(long)row * 1024 + col] = acc[m][n][r] + bv;
            }
        }
}

// ------------------------------------------------------------------
// Flash attention, 32x32x16 MFMA, swapped QK^T, in-register P via permlane,
// MFMA row-sums, no-max exp2 softmax, pre-transposed V.
// 64 q-rows per wave (2 Q-fragments) to halve LDS-read traffic per output.
// Grid: 512 flat blocks (XCD swizzle), 256 thr, 256 q-rows/block.
__global__ __launch_bounds__(256, 2) void attn_kernel(const unsigned short* __restrict__ Qh,
                                                      const unsigned short* __restrict__ Kh,
                                                      const unsigned short* __restrict__ Vt,
                                                      unsigned short* __restrict__ Om) {
    const int S = 2048;
    const int NT = S / 64;
    int flat = blockIdx.x;
    int nf_ = (flat & 7) * 64 + (flat >> 3);   // 8 XCDs x 64 contiguous
    int qt = nf_ & 7;                          // 8 q-tiles of 256 rows
    int bh = nf_ >> 3;
    int b = bh >> 4, h = bh & 15;

    int tid = threadIdx.x, wave = tid >> 6, lane = tid & 63;
    int l31 = lane & 31, hi = lane >> 5;

    __shared__ __align__(16) unsigned short Kl[3][4096];    // [kv][d] ^((kv&7)<<4)
    __shared__ __align__(16) unsigned short Vtl[3][4096];   // [d][kv] ^((d&7)<<4)

    const unsigned short* Qb = Qh + (long)bh * S * 64;
    const unsigned short* Kb = Kh + (long)bh * S * 64;
    const unsigned short* Vb = Vt + (long)bh * 64 * S;

    // pre-swizzled global sources (swizzle-on-source + swizzle-on-read, linear LDS dest)
    int colS = ((((tid & 7) * 16) ^ (((tid >> 3) & 7) << 4)) >> 1);   // elems
    const unsigned short* srcK = Kb + (tid >> 3) * 64 + colS;         // + kt*4096; i=1:+2048
    const unsigned short* srcV = Vb + (tid >> 3) * 2048 + colS;       // + kt*64;   i=1:+65536

    // Q B-fragments in registers: 2 q-blocks of 32, 4 k-slices each
    short8 aq[2][4];
    {
        const unsigned short* qrow = Qb + (long)(qt * 256 + wave * 64 + l31) * 64 + hi * 8;
#pragma unroll
        for (int qf = 0; qf < 2; ++qf)
#pragma unroll
            for (int s = 0; s < 4; ++s)
                aq[qf][s] = *(const short8*)(qrow + qf * 32 * 64 + s * 16);
    }

    f32x16 oacc[2][2], lacc[2];
#pragma unroll
    for (int r = 0; r < 16; ++r) {
        oacc[0][0][r] = 0.f; oacc[0][1][r] = 0.f;
        oacc[1][0][r] = 0.f; oacc[1][1][r] = 0.f;
        lacc[0][r] = 0.f; lacc[1][r] = 0.f;
    }

    const short8 ones8 = {0x3F80, 0x3F80, 0x3F80, 0x3F80, 0x3F80, 0x3F80, 0x3F80, 0x3F80};

    int rb0 = l31 * 128;                 // row byte (within 32-row block)
    int swz = (l31 & 7) << 4;

#define STAGE(kt, bi) do {                                              \
        const unsigned short* sk = srcK + (kt) * 4096;                  \
        gll16(sk,         (char*)Kl[bi] + wave * 1024);                 \
        gll16(sk + 2048,  (char*)Kl[bi] + 4096 + wave * 1024);          \
        const unsigned short* sv = srcV + (kt) * 64;                    \
        gll16(sv,         (char*)Vtl[bi] + wave * 1024);                \
        gll16(sv + 65536, (char*)Vtl[bi] + 4096 + wave * 1024);         \
    } while (0)

    STAGE(0, 0);
    STAGE(1, 1);

    int bi = 0, sb = 2;                  // compute buffer, stage buffer (kt+2)%3
    for (int kt = 0; kt < NT; ++kt) {
        if (kt == NT - 1) { asm volatile("s_waitcnt vmcnt(0)" ::: "memory"); }
        else              { asm volatile("s_waitcnt vmcnt(4)" ::: "memory"); }
        __builtin_amdgcn_s_barrier();
        if (kt < NT - 2) STAGE(kt + 2, sb);

        const char* KlC = (const char*)Kl[bi];
        const char* VlC = (const char*)Vtl[bi];

        // ---- S^T = K Q^T for both q-fragments (kf reused) ----
        f32x16 sacc[2][2];
#pragma unroll
        for (int r = 0; r < 16; ++r) {
            sacc[0][0][r] = 0.f; sacc[0][1][r] = 0.f;
            sacc[1][0][r] = 0.f; sacc[1][1][r] = 0.f;
        }
#pragma unroll
        for (int blk = 0; blk < 2; ++blk)
#pragma unroll
            for (int s = 0; s < 4; ++s) {
                short8 kf = *(const short8*)(KlC + blk * 4096 + rb0 + ((32 * s + 16 * hi) ^ swz));
                sacc[0][blk] = MFMA32(kf, aq[0][s], sacc[0][blk]);
                sacc[1][blk] = MFMA32(kf, aq[1][s], sacc[1][blk]);
            }

        // ---- P = exp2(S^T) (Q pre-scaled by 0.125*log2e; no max needed) ----
#pragma unroll
        for (int qf = 0; qf < 2; ++qf)
#pragma unroll
            for (int blk = 0; blk < 2; ++blk)
#pragma unroll
                for (int r = 0; r < 16; ++r) sacc[qf][blk][r] = exp2_fast(sacc[qf][blk][r]);

        // ---- per 16-kv slice: pack, permlane32_swap -> PV A-frags; vf reused ----
#pragma unroll
        for (int s = 0; s < 4; ++s) {
            const int blk = s >> 1, base = (s & 1) * 8;
            short8 pa[2];
#pragma unroll
            for (int qf = 0; qf < 2; ++qf) {
                unsigned q0 = pk_trunc(sacc[qf][blk][base + 0], sacc[qf][blk][base + 1]);
                unsigned q1 = pk_trunc(sacc[qf][blk][base + 2], sacc[qf][blk][base + 3]);
                unsigned q2 = pk_trunc(sacc[qf][blk][base + 4], sacc[qf][blk][base + 5]);
                unsigned q3 = pk_trunc(sacc[qf][blk][base + 6], sacc[qf][blk][base + 7]);
                pl32_swap(q0, q2);
                pl32_swap(q1, q3);
                uint4v pw; pw[0] = q0; pw[1] = q1; pw[2] = q2; pw[3] = q3;
                pa[qf] = __builtin_bit_cast(short8, pw);
            }
#pragma unroll
            for (int dblk = 0; dblk < 2; ++dblk) {
                short8 vf = *(const short8*)(VlC + dblk * 4096 + rb0 + ((32 * s + 16 * hi) ^ swz));
                oacc[0][dblk] = MFMA32(pa[0], vf, oacc[0][dblk]);
                oacc[1][dblk] = MFMA32(pa[1], vf, oacc[1][dblk]);
            }
            lacc[0] = MFMA32(pa[0], ones8, lacc[0]);
            lacc[1] = MFMA32(pa[1], ones8, lacc[1]);
        }
        bi = (bi == 2) ? 0 : bi + 1;
        sb = (sb == 2) ? 0 : sb + 1;
    }
#undef STAGE

    // ---- normalize + store merged [B][S][1024] ----
#pragma unroll
    for (int qf = 0; qf < 2; ++qf) {
        float inv[16];
#pragma unroll
        for (int r = 0; r < 16; ++r) inv[r] = 1.0f / lacc[qf][r];
        int qrow0 = qt * 256 + wave * 64 + qf * 32 + 4 * hi;
#pragma unroll
        for (int dblk = 0; dblk < 2; ++dblk)
#pragma unroll
            for (int r = 0; r < 16; ++r) {
                int qrow = qrow0 + (r & 3) + 8 * (r >> 2);
                int d = h * 64 + dblk * 32 + l31;
                float v = oacc[qf][dblk][r] * inv[r];
                Om[((long)b * 2048 + qrow) * 1024 + d] = f2bf(v);
            }
    }
}

// ------------------------------------------------------------------
extern "C" void kernel_launch(void* const* d_in, const int* in_sizes, int n_in,
                              void* d_out, int out_size, void* d_ws, size_t ws_size,
                              hipStream_t stream) {
    const float* v_in = (const float*)d_in[0];
    const float* k_in = (const float*)d_in[1];
    const float* q_in = (const float*)d_in[2];
    const float* wq_w = (const float*)d_in[3];
    const float* wq_b = (const float*)d_in[4];
    const float* wk_w = (const float*)d_in[5];
    const float* wk_b = (const float*)d_in[6];
    const float* wv_w = (const float*)d_in[7];
    const float* wv_b = (const float*)d_in[8];
    const float* wd_w = (const float*)d_in[9];
    const float* wd_b = (const float*)d_in[10];
    const float* pe   = (const float*)d_in[11];

    const long SZ = 8192L * 1024 * 2;
    char* ws = (char*)d_ws;
    unsigned short* xq = (unsigned short*)(ws + 0);          // xq,xk,xv contiguous
    unsigned short* xk = (unsigned short*)(ws + SZ);
    unsigned short* xv = (unsigned short*)(ws + 2 * SZ);
    unsigned short* qh = (unsigned short*)(ws + 3 * SZ);
    unsigned short* kh = (unsigned short*)(ws + 4 * SZ);
    unsigned short* vt = (unsigned short*)(ws + 5 * SZ);
    unsigned short* wqb16 = (unsigned short*)(ws + 6 * SZ);  // wq,wk,wv,wd contiguous

    pe_cast3<<<dim3(8192, 3), 256, 0, stream>>>(q_in, k_in, v_in, pe, xq, xk, xv);
    wcast4<<<dim3(1024, 4), 256, 0, stream>>>(wq_w, wk_w, wv_w, wd_w, wqb16);

    const float QSCALE = 0.125f * 1.44269504088896f;   // fold 1/sqrt(64) * log2(e)
    gemm_qkv<<<dim3(64, 8, 3), 256, 0, stream>>>(xq, wqb16, wq_b, wk_b, wv_b,
                                                 qh, kh, vt, QSCALE);
    unsigned short* om = xq;
    attn_kernel<<<512, 256, 0, stream>>>(qh, kh, vt, om);
    gemm_dense<<<dim3(64, 8), 256, 0, stream>>>(om, wqb16 + 3L * 1024 * 1024, wd_b,
                                                (float*)d_out);
}